// Round 6
// baseline (507.476 us; speedup 1.0000x reference)
//
#include <hip/hip_runtime.h>
#include <hip/hip_bf16.h>

#define T_STEPS 256
#define BATCH   512
#define HID     128
#define TBROWS  (T_STEPS * BATCH)
#define XH_STRIDE 32          // xcat as f16, 32 ushorts per row (24 used)

typedef short  bh8   __attribute__((ext_vector_type(8)));   // 8 bf16 (MFMA A/B frag)
typedef _Float16 h8  __attribute__((ext_vector_type(8)));   // 8 f16  (MFMA A/B frag)
typedef float  f32x4 __attribute__((ext_vector_type(4)));   // MFMA C/D frag

__device__ __forceinline__ unsigned short f2bf_bits(float x) {
    union { float f; unsigned int u; } a; a.f = x;
    unsigned int r = a.u + 0x7fffu + ((a.u >> 16) & 1u);   // RNE
    return (unsigned short)(r >> 16);
}
__device__ __forceinline__ unsigned short f2h_bits(float x) {
    union { _Float16 h; unsigned short u; } z; z.h = (_Float16)x; return z.u;
}
__device__ __forceinline__ unsigned int pack2h(float a, float b) {
    union { _Float16 h[2]; unsigned int u; } z;
    z.h[0] = (_Float16)a; z.h[1] = (_Float16)b; return z.u;
}
__device__ __forceinline__ unsigned int pack2bf(float a, float b) {
    return (unsigned int)f2bf_bits(a) | ((unsigned int)f2bf_bits(b) << 16);
}

#if __has_builtin(__builtin_amdgcn_rcpf)
__device__ __forceinline__ float frcp(float x) { return __builtin_amdgcn_rcpf(x); }
#else
__device__ __forceinline__ float frcp(float x) { return 1.0f / x; }
#endif
#if __has_builtin(__builtin_amdgcn_exp2f)
__device__ __forceinline__ float fexp2(float x) { return __builtin_amdgcn_exp2f(x); }
#else
__device__ __forceinline__ float fexp2(float x) { return __expf(x * 0.6931471806f); }
#endif
#define LOG2E 1.442695041f
__device__ __forceinline__ float sigf(float x) {
    return frcp(1.0f + fexp2(-x * LOG2E));
}
__device__ __forceinline__ float tanh_fast(float x) {
    return fmaf(-2.0f, frcp(1.0f + fexp2(x * (2.0f * LOG2E))), 1.0f);
}

// ===========================================================================
// Prep (unchanged): bf16 frag blobs for MLP, f16 A-frag blob for the LSTM
// combined weight Wc[512x160] (k<128 Whh, 128<=k<152 Wih, else 0), fused bias.
//   blob[(tile*KT + kt)*512 + lane*8 + j] = W[tile*16 + (lane&15)][kt*32 + (lane>>4)*8 + j]
// ===========================================================================
__device__ __forceinline__ void fragstore(unsigned short* dst, const float* W,
                                          int i, int NT, int Kreal) {
    const int j    = i & 7;
    const int lane = (i >> 3) & 63;
    const int ts   = i >> 9;
    const int nt   = ts % NT;
    const int ks   = ts / NT;
    const int n = nt * 16 + (lane & 15);
    const int k = ks * 32 + (lane >> 4) * 8 + j;
    dst[i] = (k < Kreal) ? f2bf_bits(W[n * Kreal + k]) : (unsigned short)0;
}

#define NE1 8192     // 16 tiles * 512
#define NE2 65536    // 8 kt * 16 tiles * 512
#define NE3 32768    // 8 * 8 * 512
#define NE4 2048     // 4 * 1 * 512
#define NWC 81920    // 32 mtiles * 5 ktiles * 64 * 8  (LSTM A-frags, f16)
#define NBS 512
#define PREP_TOTAL (NE1 + NE2 + NE3 + NE4 + NWC + NBS)   // 190976

__global__ __launch_bounds__(256) void prep_kernel(
    const float* __restrict__ W1, const float* __restrict__ W2,
    const float* __restrict__ W3, const float* __restrict__ W4,
    const float* __restrict__ Wih, const float* __restrict__ bih,
    const float* __restrict__ Whh, const float* __restrict__ bhh,
    unsigned short* __restrict__ w1f, unsigned short* __restrict__ w2f,
    unsigned short* __restrict__ w3f, unsigned short* __restrict__ w4f,
    unsigned short* __restrict__ wcf, float* __restrict__ bsum)
{
    int i = blockIdx.x * 256 + threadIdx.x;
    if (i < NE1) { fragstore(w1f, W1, i, 16, 25); return; }
    i -= NE1;
    if (i < NE2) { fragstore(w2f, W2, i, 16, 256); return; }
    i -= NE2;
    if (i < NE3) { fragstore(w3f, W3, i, 8, 256); return; }
    i -= NE3;
    if (i < NE4) { fragstore(w4f, W4, i, 1, 128); return; }
    i -= NE4;
    if (i < NWC) {
        const int j    = i & 7;
        const int lane = (i >> 3) & 63;
        const int ts   = i >> 9;          // mt*5 + kt
        const int mt   = ts / 5;
        const int kt   = ts - mt * 5;
        const int m = mt * 16 + (lane & 15);
        const int k = kt * 32 + (lane >> 4) * 8 + j;
        float v = 0.0f;
        if (k < 128)      v = Whh[m * 128 + k];
        else if (k < 152) v = Wih[m * 24 + (k - 128)];
        wcf[i] = f2h_bits(v);
        return;
    }
    i -= NWC;
    if (i < NBS) bsum[i] = bih[i] + bhh[i];
}

// ===========================================================================
// Encoder v2 (round-5 structure, now with VGPR headroom so accs stay
// register-resident): weights = A operand, samples = B operand, 32 samples
// per wave, acts in LDS [sample][neuron] bf16. Block = 256 thr = 128 samples.
// ===========================================================================
#define ASTRIDE 264

__global__ __launch_bounds__(256, 2) void encoder_kernel(
    const float* __restrict__ img,
    const float* __restrict__ loc,
    const float* __restrict__ msg,
    const int*   __restrict__ done,
    const float* __restrict__ B1, const float* __restrict__ B2,
    const float* __restrict__ B3, const float* __restrict__ B4,
    const float* __restrict__ Wl, const float* __restrict__ Bl,
    const float* __restrict__ Wm, const float* __restrict__ Bm,
    const unsigned short* __restrict__ w1f, const unsigned short* __restrict__ w2f,
    const unsigned short* __restrict__ w3f, const unsigned short* __restrict__ w4f,
    unsigned short* __restrict__ xcat_h)
{
    __shared__ __align__(16) unsigned short actA[4][32][ASTRIDE];
    __shared__ __align__(16) unsigned short actB[4][32][ASTRIDE];

    const int tid  = threadIdx.x;
    const int w    = tid >> 6;
    const int lane = tid & 63;
    const int n    = lane & 15;       // sample within group
    const int quad = lane >> 4;
    const int wrow0 = blockIdx.x * 128 + w * 32;

    // loc/msg encoders: 128 samples per block, 1 thread each
    if (tid < 128) {
        const int grow = blockIdx.x * 128 + tid;
        const float l0 = loc[(size_t)grow * 2 + 0] * 0.1f;
        const float l1 = loc[(size_t)grow * 2 + 1] * 0.1f;
        #pragma unroll
        for (int c = 0; c < 4; ++c)
            xcat_h[(size_t)grow * XH_STRIDE + 16 + c] =
                f2h_bits(fmaf(Wl[c * 2 + 0], l0, fmaf(Wl[c * 2 + 1], l1, Bl[c])));
        const float mm = (1.0f - (float)done[grow]) * msg[grow];
        #pragma unroll
        for (int c = 0; c < 4; ++c)
            xcat_h[(size_t)grow * XH_STRIDE + 20 + c] =
                f2h_bits(fmaxf(fmaf(Wm[c], mm, Bm[c]), 0.0f));
    }

    const f32x4 zero4 = {0.0f, 0.0f, 0.0f, 0.0f};

    // ---- L1: 25(pad32) -> 256 ----
    {
        bh8 bimg[2];
        #pragma unroll
        for (int sg = 0; sg < 2; ++sg) {
            const size_t grow = wrow0 + sg * 16 + n;
            #pragma unroll
            for (int j = 0; j < 8; ++j) {
                const int k = quad * 8 + j;
                const float v = (k < 25) ? img[grow * 25 + k] * (1.0f / 255.0f) : 0.0f;
                bimg[sg][j] = (short)f2bf_bits(v);
            }
        }
        f32x4 a1[16][2];
        #pragma unroll
        for (int mt = 0; mt < 16; ++mt) {
            const bh8 a = *reinterpret_cast<const bh8*>(w1f + (size_t)(mt * 64 + lane) * 8);
            a1[mt][0] = __builtin_amdgcn_mfma_f32_16x16x32_bf16(a, bimg[0], zero4, 0, 0, 0);
            a1[mt][1] = __builtin_amdgcn_mfma_f32_16x16x32_bf16(a, bimg[1], zero4, 0, 0, 0);
        }
        #pragma unroll
        for (int mt = 0; mt < 16; ++mt) {
            const float4 bv = *reinterpret_cast<const float4*>(B1 + mt * 16 + quad * 4);
            #pragma unroll
            for (int sg = 0; sg < 2; ++sg) {
                const float v0 = fmaxf(a1[mt][sg][0] + bv.x, 0.0f);
                const float v1 = fmaxf(a1[mt][sg][1] + bv.y, 0.0f);
                const float v2 = fmaxf(a1[mt][sg][2] + bv.z, 0.0f);
                const float v3 = fmaxf(a1[mt][sg][3] + bv.w, 0.0f);
                uint2 pk; pk.x = pack2bf(v0, v1); pk.y = pack2bf(v2, v3);
                *reinterpret_cast<uint2*>(&actA[w][sg * 16 + n][mt * 16 + quad * 4]) = pk;
            }
        }
    }
    __syncthreads();

    // ---- L2: 256 -> 256 ----
    {
        f32x4 a2[16][2];
        #pragma unroll
        for (int mt = 0; mt < 16; ++mt) { a2[mt][0] = zero4; a2[mt][1] = zero4; }
        #pragma unroll
        for (int kt = 0; kt < 8; ++kt) {
            const bh8 b0 = *reinterpret_cast<const bh8*>(&actA[w][n][kt * 32 + quad * 8]);
            const bh8 b1 = *reinterpret_cast<const bh8*>(&actA[w][16 + n][kt * 32 + quad * 8]);
            #pragma unroll
            for (int mt = 0; mt < 16; ++mt) {
                const bh8 a = *reinterpret_cast<const bh8*>(
                    w2f + (size_t)((kt * 16 + mt) * 64 + lane) * 8);
                a2[mt][0] = __builtin_amdgcn_mfma_f32_16x16x32_bf16(a, b0, a2[mt][0], 0, 0, 0);
                a2[mt][1] = __builtin_amdgcn_mfma_f32_16x16x32_bf16(a, b1, a2[mt][1], 0, 0, 0);
            }
        }
        #pragma unroll
        for (int mt = 0; mt < 16; ++mt) {
            const float4 bv = *reinterpret_cast<const float4*>(B2 + mt * 16 + quad * 4);
            #pragma unroll
            for (int sg = 0; sg < 2; ++sg) {
                const float v0 = fmaxf(a2[mt][sg][0] + bv.x, 0.0f);
                const float v1 = fmaxf(a2[mt][sg][1] + bv.y, 0.0f);
                const float v2 = fmaxf(a2[mt][sg][2] + bv.z, 0.0f);
                const float v3 = fmaxf(a2[mt][sg][3] + bv.w, 0.0f);
                uint2 pk; pk.x = pack2bf(v0, v1); pk.y = pack2bf(v2, v3);
                *reinterpret_cast<uint2*>(&actB[w][sg * 16 + n][mt * 16 + quad * 4]) = pk;
            }
        }
    }
    __syncthreads();

    // ---- L3: 256 -> 128 ----
    {
        f32x4 a3[8][2];
        #pragma unroll
        for (int mt = 0; mt < 8; ++mt) { a3[mt][0] = zero4; a3[mt][1] = zero4; }
        #pragma unroll
        for (int kt = 0; kt < 8; ++kt) {
            const bh8 b0 = *reinterpret_cast<const bh8*>(&actB[w][n][kt * 32 + quad * 8]);
            const bh8 b1 = *reinterpret_cast<const bh8*>(&actB[w][16 + n][kt * 32 + quad * 8]);
            #pragma unroll
            for (int mt = 0; mt < 8; ++mt) {
                const bh8 a = *reinterpret_cast<const bh8*>(
                    w3f + (size_t)((kt * 8 + mt) * 64 + lane) * 8);
                a3[mt][0] = __builtin_amdgcn_mfma_f32_16x16x32_bf16(a, b0, a3[mt][0], 0, 0, 0);
                a3[mt][1] = __builtin_amdgcn_mfma_f32_16x16x32_bf16(a, b1, a3[mt][1], 0, 0, 0);
            }
        }
        #pragma unroll
        for (int mt = 0; mt < 8; ++mt) {
            const float4 bv = *reinterpret_cast<const float4*>(B3 + mt * 16 + quad * 4);
            #pragma unroll
            for (int sg = 0; sg < 2; ++sg) {
                const float v0 = fmaxf(a3[mt][sg][0] + bv.x, 0.0f);
                const float v1 = fmaxf(a3[mt][sg][1] + bv.y, 0.0f);
                const float v2 = fmaxf(a3[mt][sg][2] + bv.z, 0.0f);
                const float v3 = fmaxf(a3[mt][sg][3] + bv.w, 0.0f);
                uint2 pk; pk.x = pack2bf(v0, v1); pk.y = pack2bf(v2, v3);
                *reinterpret_cast<uint2*>(&actA[w][sg * 16 + n][mt * 16 + quad * 4]) = pk;
            }
        }
    }
    __syncthreads();

    // ---- L4: 128 -> 16, write f16 to xcat ----
    {
        f32x4 a4[2] = {zero4, zero4};
        #pragma unroll
        for (int kt = 0; kt < 4; ++kt) {
            const bh8 b0 = *reinterpret_cast<const bh8*>(&actA[w][n][kt * 32 + quad * 8]);
            const bh8 b1 = *reinterpret_cast<const bh8*>(&actA[w][16 + n][kt * 32 + quad * 8]);
            const bh8 a = *reinterpret_cast<const bh8*>(w4f + (size_t)(kt * 64 + lane) * 8);
            a4[0] = __builtin_amdgcn_mfma_f32_16x16x32_bf16(a, b0, a4[0], 0, 0, 0);
            a4[1] = __builtin_amdgcn_mfma_f32_16x16x32_bf16(a, b1, a4[1], 0, 0, 0);
        }
        const float4 bv = *reinterpret_cast<const float4*>(B4 + quad * 4);
        #pragma unroll
        for (int sg = 0; sg < 2; ++sg) {
            const int grow = wrow0 + sg * 16 + n;
            const float v0 = fmaxf(a4[sg][0] + bv.x, 0.0f);
            const float v1 = fmaxf(a4[sg][1] + bv.y, 0.0f);
            const float v2 = fmaxf(a4[sg][2] + bv.z, 0.0f);
            const float v3 = fmaxf(a4[sg][3] + bv.w, 0.0f);
            uint2 pk; pk.x = pack2h(v0, v1); pk.y = pack2h(v2, v3);
            *reinterpret_cast<uint2*>(xcat_h + (size_t)grow * XH_STRIDE + quad * 4) = pk;
        }
    }
}

// ===========================================================================
// LSTM scan v4: 512 blocks x 1 batch-col, 256 threads (4 waves), 2 blocks/CU.
// launch_bounds(256,2) -> VGPR cap 256: the 160-VGPR weight set stays
// register-resident (round 5 spilled it to scratch at the default cap: 7 GB
// FETCH_SIZE). h-history staged in LDS, flushed as float4 every 8 steps so
// the pre-barrier vmcnt(0) drain pays store latency 1 step in 8.
// ===========================================================================
#define HXS 168      // hx row stride in shorts (336 B, 16B-aligned)

__global__ __launch_bounds__(256, 2) void lstm_kernel(
    const unsigned short* __restrict__ xcat_h,
    const int*   __restrict__ done,
    const float* __restrict__ h0,
    const float* __restrict__ c0,
    const unsigned short* __restrict__ wcf,   // A-frag blob [32][5][64][8] f16
    const float* __restrict__ bsum,           // [512] = bih + bhh
    float* __restrict__ out)
{
    __shared__ __align__(16) unsigned short hx[2][16][HXS];
    __shared__ __align__(16) float gbuf[130][4];
    __shared__ __align__(16) float hist[8][HID];

    const int tid  = threadIdx.x;
    const int w    = tid >> 6;        // wave 0..3
    const int lane = tid & 63;
    const int n    = lane & 15;       // batch column (only 0 real)
    const int quad = lane >> 4;
    const int b    = blockIdx.x;

    // A-frags: mtiles g*8 + w + 4*h, g in 0..3, h in 0..1  (160 VGPRs)
    h8 wf[2][4][5];
    #pragma unroll
    for (int h = 0; h < 2; ++h)
        #pragma unroll
        for (int g = 0; g < 4; ++g)
            #pragma unroll
            for (int kt = 0; kt < 5; ++kt)
                wf[h][g][kt] = *reinterpret_cast<const h8*>(
                    wcf + (size_t)(((g * 8 + w + 4 * h) * 5 + kt) * 64 + lane) * 8);

    const int tu = tid & 127;          // owned unit (threads tid<128)
    float bi_t[4];
    #pragma unroll
    for (int g = 0; g < 4; ++g) bi_t[g] = bsum[g * 128 + tu];

    float c_ = 0.0f, hl = 0.0f;
    if (tid < 128) c_ = c0[(size_t)b * HID + tu];

    // zero hx (rows 1..15 and the k>=152 pad stay zero forever)
    for (int i = tid; i < (int)(sizeof(hx) / 4); i += 256)
        reinterpret_cast<unsigned int*>(hx)[i] = 0u;
    __syncthreads();

    int mc = done[b];                  // done(0)
    int mn = done[BATCH + b];          // done(1)
    if (tid < 128) {
        const float h0v = h0[(size_t)b * HID + tu];
        hx[0][0][tu] = f2h_bits(h0v * (1.0f - (float)mc));
    }
    if (tid < 12)
        reinterpret_cast<unsigned int*>(&hx[0][0][128])[tid] =
            reinterpret_cast<const unsigned int*>(xcat_h + (size_t)b * XH_STRIDE)[tid];
    __syncthreads();

    #pragma unroll 2
    for (int s = 0; s < T_STEPS; ++s) {
        const int buf = s & 1;

        // B-frags (cols >=1 read zero rows)
        h8 bf[5];
        #pragma unroll
        for (int kt = 0; kt < 5; ++kt)
            bf[kt] = *reinterpret_cast<const h8*>(&hx[buf][n][kt * 32 + quad * 8]);

        // prefetch x(s+1), done(s+2)
        unsigned int xreg = 0;
        if (tid < 12) {
            const int rowx = (s + 1 < T_STEPS ? s + 1 : T_STEPS - 1) * BATCH + b;
            xreg = reinterpret_cast<const unsigned int*>(xcat_h + (size_t)rowx * XH_STRIDE)[tid];
        }
        const int mf = done[(s + 2 < T_STEPS ? s + 2 : T_STEPS - 1) * BATCH + b];

        // gates = Wc @ [h;x]
        f32x4 acc[2][4];
        #pragma unroll
        for (int h = 0; h < 2; ++h)
            #pragma unroll
            for (int g = 0; g < 4; ++g) acc[h][g] = (f32x4){0.0f, 0.0f, 0.0f, 0.0f};
        #pragma unroll
        for (int kt = 0; kt < 5; ++kt)
            #pragma unroll
            for (int h = 0; h < 2; ++h)
                #pragma unroll
                for (int g = 0; g < 4; ++g)
                    acc[h][g] = __builtin_amdgcn_mfma_f32_16x16x32_f16(
                        wf[h][g][kt], bf[kt], acc[h][g], 0, 0, 0);

        // transpose-write gates (col 0 holders only)
        if (n == 0) {
            #pragma unroll
            for (int h = 0; h < 2; ++h) {
                const int ub = (w + 4 * h) * 16 + quad * 4;
                #pragma unroll
                for (int r = 0; r < 4; ++r) {
                    float4 gv;
                    gv.x = acc[h][0][r]; gv.y = acc[h][1][r];
                    gv.z = acc[h][2][r]; gv.w = acc[h][3][r];
                    *reinterpret_cast<float4*>(&gbuf[ub + r][0]) = gv;
                }
            }
        }
        __syncthreads();

        // gate math: 1 (col,unit) tuple per thread (tid<128)
        if (tid < 128) {
            const float4 gv = *reinterpret_cast<const float4*>(&gbuf[tu][0]);
            const float mcur = 1.0f - (float)mc;
            const float mnxt = 1.0f - (float)mn;
            const float gi = gv.x + bi_t[0];
            const float gf = gv.y + bi_t[1];
            const float gg = gv.z + bi_t[2];
            const float go = gv.w + bi_t[3];
            const float cn = sigf(gf) * (c_ * mcur) + sigf(gi) * tanh_fast(gg);
            const float hn = sigf(go) * tanh_fast(cn);
            c_ = cn; hl = hn;
            hist[s & 7][tu] = hn;
            hx[buf ^ 1][0][tu] = f2h_bits(hn * mnxt);
        }
        if (tid < 12)
            reinterpret_cast<unsigned int*>(&hx[buf ^ 1][0][128])[tid] = xreg;
        mc = mn; mn = mf;
        __syncthreads();

        // bulk-flush 8 steps of h (stores drain at next step's barrier)
        if ((s & 7) == 7) {
            const int sc = tid >> 5;          // 0..7
            const int j  = tid & 31;
            const float4 v = *reinterpret_cast<const float4*>(&hist[sc][j * 4]);
            const int srow = (s - 7 + sc) * BATCH + b;
            *reinterpret_cast<float4*>(out + (size_t)srow * HID + j * 4) = v;
        }
    }

    if (tid < 128) {
        const size_t base = (size_t)TBROWS * HID;
        out[base + (size_t)b * HID + tu] = hl;
        out[base + (size_t)BATCH * HID + (size_t)b * HID + tu] = c_;
    }
}

// ===========================================================================
extern "C" void kernel_launch(void* const* d_in, const int* in_sizes, int n_in,
                              void* d_out, int out_size, void* d_ws, size_t ws_size,
                              hipStream_t stream) {
    const float* img  = (const float*)d_in[0];
    const float* loc  = (const float*)d_in[1];
    const float* msg  = (const float*)d_in[2];
    const int*   done = (const int*)d_in[3];
    const float* h0   = (const float*)d_in[4];
    const float* c0   = (const float*)d_in[5];
    const float* W1   = (const float*)d_in[6];
    const float* B1   = (const float*)d_in[7];
    const float* W2   = (const float*)d_in[8];
    const float* B2   = (const float*)d_in[9];
    const float* W3   = (const float*)d_in[10];
    const float* B3   = (const float*)d_in[11];
    const float* W4   = (const float*)d_in[12];
    const float* B4   = (const float*)d_in[13];
    const float* Wl   = (const float*)d_in[14];
    const float* Bl   = (const float*)d_in[15];
    const float* Wm   = (const float*)d_in[16];
    const float* Bm   = (const float*)d_in[17];
    const float* Wih  = (const float*)d_in[18];
    const float* bih  = (const float*)d_in[19];
    const float* Whh  = (const float*)d_in[20];
    const float* bhh  = (const float*)d_in[21];

    // workspace layout
    char* wsb = (char*)d_ws;
    unsigned short* xcat_h = (unsigned short*)wsb;                   // 8 388 608 B
    unsigned short* w1f = (unsigned short*)(wsb + (size_t)TBROWS * XH_STRIDE * 2);
    unsigned short* w2f = w1f + NE1;
    unsigned short* w3f = w2f + NE2;
    unsigned short* w4f = w3f + NE3;
    unsigned short* wcf = w4f + NE4;
    float*          bsum = (float*)(wcf + NWC);

    float* out = (float*)d_out;

    prep_kernel<<<(PREP_TOTAL + 255) / 256, 256, 0, stream>>>(
        W1, W2, W3, W4, Wih, bih, Whh, bhh,
        w1f, w2f, w3f, w4f, wcf, bsum);
    encoder_kernel<<<TBROWS / 128, 256, 0, stream>>>(
        img, loc, msg, done, B1, B2, B3, B4, Wl, Bl, Wm, Bm,
        w1f, w2f, w3f, w4f, xcat_h);
    lstm_kernel<<<BATCH, 256, 0, stream>>>(
        xcat_h, done, h0, c0, wcf, bsum, out);
}